// Round 4
// baseline (228.722 us; speedup 1.0000x reference)
//
#include <hip/hip_runtime.h>
#include <hip/hip_bf16.h>
#include <math.h>

// Flash attention, bf16 MFMA 16x16x32, fp32 accumulate. B=2,H=12,S=2048,D=64.
// R4: BQ=64, 128-thread blocks (2 waves x 32 q) -> 768 blocks, ~5 blocks/CU.
// QK^T computed TRANSPOSED (A=K, B=Q): C-layout row=k, col=q, so each lane
// holds 4 consecutive k for one q -> P written with b64 stores; mask needs
// only 2 coalesced u64 loads per thread per tile. Row-sum l via ones-MFMA.
// All three prepasses fused into one kernel.

#define BB 2
#define HH 12
#define SS 2048
#define DD 64
#define BQ 64
#define BK 64
#define NT (SS / BK)
#define LQ 72   // LDS row stride in bf16 (144 B = 9*16: b128-aligned rows)
#define LT 76   // transpose LDS tile stride

typedef __attribute__((ext_vector_type(8))) short bf8_t;   // 8 bf16 = 4 VGPR
typedef __attribute__((ext_vector_type(4))) short bf4_t;
typedef __attribute__((ext_vector_type(4))) float f4_t;
typedef unsigned long long u64;

__device__ __forceinline__ short f2bf(float f) {
    __hip_bfloat16 h = __float2bfloat16(f);
    return *reinterpret_cast<short*>(&h);
}

// ---------- fused prepass ----------
// grid = BB*SS = 4096 blocks x 256 threads.
//   all blocks:      pack mask row bx -> Mb[bx][0..31] (u64 bitmask)
//   bx <  768:       V [bh][s][d] fp32 -> Vt [bh][d][s] bf16 (64-row tile)
//   768 <= bx <2304: K fp32 -> Kb bf16 (2048-elem chunk)
__global__ __launch_bounds__(256) void prepass(
    const float* __restrict__ V, const float* __restrict__ K,
    const int* __restrict__ M, unsigned short* __restrict__ Vt,
    unsigned short* __restrict__ Kb, u64* __restrict__ Mb)
{
    __shared__ unsigned short Ts[64][LT];
    const int bx  = blockIdx.x;
    const int tid = threadIdx.x;
    const int w    = tid >> 6;
    const int lane = tid & 63;

    // ---- mask row bx
    {
        const int* src = M + (size_t)bx * SS;
        #pragma unroll
        for (int p = 0; p < 8; ++p) {
            int k = p * 256 + w * 64 + lane;
            u64 bm = __ballot(src[k] != 0);
            if (lane == 0) Mb[(size_t)bx * (SS / 64) + p * 4 + w] = bm;
        }
    }

    if (bx < 768) {
        // ---- V transpose tile: s0 = (bx&31)*64, bh = bx>>5
        const int s0 = (bx & 31) * 64;
        const int bh = bx >> 5;
        const float* Vg = V + (size_t)bh * SS * DD;
        #pragma unroll
        for (int pass = 0; pass < 4; ++pass) {
            int c = tid + pass * 256;
            int r = c >> 4, col = (c & 15) * 4;
            float4 v = *(const float4*)(Vg + (size_t)(s0 + r) * DD + col);
            bf4_t p; p.x = f2bf(v.x); p.y = f2bf(v.y); p.z = f2bf(v.z); p.w = f2bf(v.w);
            *(bf4_t*)&Ts[r][col] = p;
        }
        __syncthreads();
        unsigned short* Vo = Vt + (size_t)bh * DD * SS;
        #pragma unroll
        for (int pass = 0; pass < 2; ++pass) {
            int c = tid + pass * 256;
            int d = c >> 3, sc = (c & 7) * 8;
            unsigned short t[8];
            #pragma unroll
            for (int u = 0; u < 8; ++u) t[u] = Ts[sc + u][d];
            uint4 o;
            o.x = (unsigned)t[0] | ((unsigned)t[1] << 16);
            o.y = (unsigned)t[2] | ((unsigned)t[3] << 16);
            o.z = (unsigned)t[4] | ((unsigned)t[5] << 16);
            o.w = (unsigned)t[6] | ((unsigned)t[7] << 16);
            *(uint4*)(Vo + (size_t)d * SS + s0 + sc) = o;
        }
    } else if (bx < 2304) {
        // ---- K convert chunk
        size_t i = ((size_t)(bx - 768) * 256 + tid) * 8;
        float4 a = *(const float4*)(K + i);
        float4 b = *(const float4*)(K + i + 4);
        uint4 o;
        o.x = (unsigned short)f2bf(a.x) | ((unsigned)(unsigned short)f2bf(a.y) << 16);
        o.y = (unsigned short)f2bf(a.z) | ((unsigned)(unsigned short)f2bf(a.w) << 16);
        o.z = (unsigned short)f2bf(b.x) | ((unsigned)(unsigned short)f2bf(b.y) << 16);
        o.w = (unsigned short)f2bf(b.z) | ((unsigned)(unsigned short)f2bf(b.w) << 16);
        *(uint4*)(Kb + i) = o;
    }
}

// ---------- main flash-attention kernel ----------
__global__ __launch_bounds__(128, 2) void attn_fwd(
    const float* __restrict__ Q, const unsigned short* __restrict__ Kb,
    const unsigned short* __restrict__ Vt, const u64* __restrict__ Mb,
    float* __restrict__ O)
{
    __shared__ unsigned short Ks[BK][LQ];
    __shared__ unsigned short Vts[DD][LQ];
    __shared__ unsigned short Ps[BQ][LQ];

    const int tid  = threadIdx.x;
    const int w    = tid >> 6;        // wave 0..1
    const int lane = tid & 63;
    const int quad = lane >> 4;
    const int l16  = lane & 15;
    const int q0   = blockIdx.x * BQ;
    const int bh   = blockIdx.y;
    const int b    = bh / HH;
    const int qbase = w * 32;         // this wave's first query row in tile

    const float*          Qg = Q  + (size_t)bh * SS * DD;
    const unsigned short* Kg = Kb + (size_t)bh * SS * DD;
    const unsigned short* Vg = Vt + (size_t)bh * DD * SS;
    float*                Og = O  + (size_t)bh * SS * DD;
    const u64*            Mg = Mb + (size_t)b * SS * (SS / 64);

    // ---- loop-invariant Q B-frags (rows q), 1/8 scale folded (exact)
    bf8_t bq[2][2];
    #pragma unroll
    for (int qf = 0; qf < 2; ++qf)
        #pragma unroll
        for (int ks = 0; ks < 2; ++ks) {
            const float* qp = Qg + (size_t)(q0 + qbase + qf * 16 + l16) * DD
                                 + ks * 32 + quad * 8;
            float4 x = *(const float4*)qp;
            float4 y = *(const float4*)(qp + 4);
            bf8_t f;
            f[0] = f2bf(x.x * 0.125f); f[1] = f2bf(x.y * 0.125f);
            f[2] = f2bf(x.z * 0.125f); f[3] = f2bf(x.w * 0.125f);
            f[4] = f2bf(y.x * 0.125f); f[5] = f2bf(y.y * 0.125f);
            f[6] = f2bf(y.z * 0.125f); f[7] = f2bf(y.w * 0.125f);
            bq[qf][ks] = f;
        }

    // ---- ones B-frag: column 0 of a virtual ones matrix -> l in D col 0
    bf8_t onesf;
    {
        short ov = (l16 == 0) ? (short)0x3F80 : (short)0;
        #pragma unroll
        for (int j = 0; j < 8; ++j) onesf[j] = ov;
    }

    f4_t oacc[2][4], lacc[2];
    #pragma unroll
    for (int qf = 0; qf < 2; ++qf) {
        lacc[qf] = (f4_t){0.f, 0.f, 0.f, 0.f};
        #pragma unroll
        for (int nf = 0; nf < 4; ++nf) oacc[qf][nf] = (f4_t){0.f, 0.f, 0.f, 0.f};
    }

    // ---- prefetch registers (K/V tiles + this wave's mask words)
    uint4 kpf[4], vpf[4];
    u64   mpf[2];
    const int scol = (tid & 7) * 8;
    auto prefetch = [&](int t) {
        const int k0 = t * BK;
        #pragma unroll
        for (int p = 0; p < 4; ++p) {
            int r = (tid + p * 128) >> 3;
            kpf[p] = *(const uint4*)(Kg + (size_t)(k0 + r) * DD + scol);
            vpf[p] = *(const uint4*)(Vg + (size_t)r * SS + k0 + scol);
        }
        #pragma unroll
        for (int qf = 0; qf < 2; ++qf)
            mpf[qf] = Mg[(size_t)(q0 + qbase + qf * 16 + l16) * (SS / 64) + t];
    };
    prefetch(0);

    for (int t = 0; t < NT; ++t) {
        __syncthreads();                 // prior tile's LDS readers done
        #pragma unroll
        for (int p = 0; p < 4; ++p) {
            int r = (tid + p * 128) >> 3;
            *(uint4*)&Ks[r][scol]  = kpf[p];
            *(uint4*)&Vts[r][scol] = vpf[p];
        }
        u64 cm[2] = {mpf[0] >> (quad * 4), mpf[1] >> (quad * 4)};
        __syncthreads();
        if (t + 1 < NT) prefetch(t + 1);     // loads in flight during compute

        // ---- S^T = K_tile . Q_tile^T : D[k][q], 4 kf x 2 qf frags
        f4_t sacc[4][2];
        #pragma unroll
        for (int kf = 0; kf < 4; ++kf) {
            bf8_t ak0 = *(const bf8_t*)&Ks[kf * 16 + l16][quad * 8];
            bf8_t ak1 = *(const bf8_t*)&Ks[kf * 16 + l16][32 + quad * 8];
            #pragma unroll
            for (int qf = 0; qf < 2; ++qf) {
                f4_t a = (f4_t){0.f, 0.f, 0.f, 0.f};
                a = __builtin_amdgcn_mfma_f32_16x16x32_bf16(ak0, bq[qf][0], a, 0, 0, 0);
                a = __builtin_amdgcn_mfma_f32_16x16x32_bf16(ak1, bq[qf][1], a, 0, 0, 0);
                sacc[kf][qf] = a;
            }
        }

        // ---- masked exp; lane holds k = kf*16+quad*4+r for q = qf*16+l16
        // -> pack 4 consecutive k as bf16, single b64 LDS write
        #pragma unroll
        for (int qf = 0; qf < 2; ++qf) {
            const int prow = qbase + qf * 16 + l16;
            #pragma unroll
            for (int kf = 0; kf < 4; ++kf) {
                bf4_t pk;
                #pragma unroll
                for (int r = 0; r < 4; ++r) {
                    float e = __expf(sacc[kf][qf][r]);
                    e = ((cm[qf] >> (kf * 16 + r)) & 1ull) ? e : 0.f;
                    pk[r] = f2bf(e);
                }
                *(bf4_t*)&Ps[prow][kf * 16 + quad * 4] = pk;
            }
        }

        // ---- P A-frags (wave-private rows, in-order LDS: no barrier)
        bf8_t ap[2][2];
        #pragma unroll
        for (int qf = 0; qf < 2; ++qf) {
            ap[qf][0] = *(const bf8_t*)&Ps[qbase + qf * 16 + l16][quad * 8];
            ap[qf][1] = *(const bf8_t*)&Ps[qbase + qf * 16 + l16][32 + quad * 8];
            lacc[qf] = __builtin_amdgcn_mfma_f32_16x16x32_bf16(ap[qf][0], onesf, lacc[qf], 0, 0, 0);
            lacc[qf] = __builtin_amdgcn_mfma_f32_16x16x32_bf16(ap[qf][1], onesf, lacc[qf], 0, 0, 0);
        }

        // ---- PV
        #pragma unroll
        for (int nf = 0; nf < 4; ++nf) {
            bf8_t bv0 = *(const bf8_t*)&Vts[nf * 16 + l16][quad * 8];
            bf8_t bv1 = *(const bf8_t*)&Vts[nf * 16 + l16][32 + quad * 8];
            #pragma unroll
            for (int qf = 0; qf < 2; ++qf) {
                oacc[qf][nf] = __builtin_amdgcn_mfma_f32_16x16x32_bf16(ap[qf][0], bv0, oacc[qf][nf], 0, 0, 0);
                oacc[qf][nf] = __builtin_amdgcn_mfma_f32_16x16x32_bf16(ap[qf][1], bv1, oacc[qf][nf], 0, 0, 0);
            }
        }
    }

    // ---- epilogue: l is in D col 0 (lane l16==0 of each quad); normalize
    #pragma unroll
    for (int qf = 0; qf < 2; ++qf)
        #pragma unroll
        for (int r = 0; r < 4; ++r) {
            float lv  = __shfl(lacc[qf][r], (lane & 48));
            float inv = 1.f / lv;
            const int row = q0 + qbase + qf * 16 + quad * 4 + r;
            #pragma unroll
            for (int nf = 0; nf < 4; ++nf)
                Og[(size_t)row * DD + nf * 16 + l16] = oacc[qf][nf][r] * inv;
        }
}

extern "C" void kernel_launch(void* const* d_in, const int* in_sizes, int n_in,
                              void* d_out, int out_size, void* d_ws, size_t ws_size,
                              hipStream_t stream) {
    const float* Q = (const float*)d_in[0];
    const float* K = (const float*)d_in[1];
    const float* V = (const float*)d_in[2];
    const int*   M = (const int*)d_in[3];
    float*       O = (float*)d_out;

    unsigned short* Vt = (unsigned short*)d_ws;                    // 6.29 MB
    unsigned short* Kb = Vt + (size_t)BB * HH * SS * DD;           // 6.29 MB
    u64*            Mb = (u64*)(Kb + (size_t)BB * HH * SS * DD);   // 1.05 MB

    prepass<<<dim3(BB * SS), 256, 0, stream>>>(V, K, M, Vt, Kb, Mb);
    attn_fwd<<<dim3(SS / BQ, BB * HH), 128, 0, stream>>>(Q, Kb, Vt, Mb, O);
}

// Round 5
// 167.743 us; speedup vs baseline: 1.3635x; 1.3635x over previous
//
#include <hip/hip_runtime.h>
#include <hip/hip_bf16.h>
#include <math.h>

// Flash attention, bf16 MFMA 16x16x32, fp32 accumulate. B=2,H=12,S=2048,D=64.
// R5: split-K (G=2) for grid parallelism (1536 blocks); exp without max makes
// partials exactly additive: O = (O_g0 + O_g1) / (l_g0 + l_g1).
// Staging via global_load_lds width=16 into XOR-swizzled LDS (no VGPR round
// trip -> no spill). S^T MFMA order: b64 P writes, coalesced transposed mask.

#define BB 2
#define HH 12
#define SS 2048
#define DD 64
#define BQ 64
#define BK 64
#define GG 2
#define KG (SS / GG)      // 1024 keys per group
#define NTG (KG / BK)     // 16 tiles per group
#define LP 72             // Ps row stride (bf16)
#define LT 76             // prepass transpose stride
#define NROWS (BB * HH * SS)

typedef __attribute__((ext_vector_type(8))) short bf8_t;
typedef __attribute__((ext_vector_type(4))) short bf4_t;
typedef __attribute__((ext_vector_type(4))) float f4_t;
typedef unsigned long long u64;

__device__ __forceinline__ short f2bf(float f) {
    __hip_bfloat16 h = __float2bfloat16(f);
    return *reinterpret_cast<short*>(&h);
}

__device__ __forceinline__ void gl_lds16(const void* g, void* l) {
    __builtin_amdgcn_global_load_lds(
        (const __attribute__((address_space(1))) unsigned*)(g),
        (__attribute__((address_space(3))) unsigned*)(l), 16, 0, 0);
}

// swizzled tile: element (row, c8-chunk) lives at chunk row*8 + (c8 ^ (row&7))
__device__ __forceinline__ bf8_t ldfrag(const unsigned short* buf, int row, int c8) {
    return *(const bf8_t*)&buf[((row << 3) | (c8 ^ (row & 7))) << 3];
}

// ---------- fused prepass ----------
// grid = BB*SS = 4096 blocks x 256.
//  all blocks: pack mask row -> Mbt[b][word][row] (TRANSPOSED for coalescing)
//  bx <  768 : V [bh][s][d] fp32 -> Vt [bh][d][s] bf16 (64-row tile)
//  768..2304 : K fp32 -> Kb bf16
__global__ __launch_bounds__(256) void prepass(
    const float* __restrict__ V, const float* __restrict__ K,
    const int* __restrict__ M, unsigned short* __restrict__ Vt,
    unsigned short* __restrict__ Kb, u64* __restrict__ Mbt)
{
    __shared__ unsigned short Ts[64][LT];
    const int bx   = blockIdx.x;
    const int tid  = threadIdx.x;
    const int w    = tid >> 6;
    const int lane = tid & 63;
    const int b    = bx >> 11;
    const int row  = bx & 2047;

    {   // mask row bx -> 32 words, transposed layout [b][word][row]
        const int* src = M + (size_t)bx * SS;
        #pragma unroll
        for (int p = 0; p < 8; ++p) {
            int k = p * 256 + w * 64 + lane;
            u64 bm = __ballot(src[k] != 0);
            if (lane == 0)
                Mbt[(size_t)b * 32 * SS + (size_t)(p * 4 + w) * SS + row] = bm;
        }
    }

    if (bx < 768) {
        const int s0 = (bx & 31) * 64;
        const int bh = bx >> 5;
        const float* Vg = V + (size_t)bh * SS * DD;
        #pragma unroll
        for (int pass = 0; pass < 4; ++pass) {
            int c = tid + pass * 256;
            int r = c >> 4, col = (c & 15) * 4;
            float4 v = *(const float4*)(Vg + (size_t)(s0 + r) * DD + col);
            bf4_t p; p.x = f2bf(v.x); p.y = f2bf(v.y); p.z = f2bf(v.z); p.w = f2bf(v.w);
            *(bf4_t*)&Ts[r][col] = p;
        }
        __syncthreads();
        unsigned short* Vo = Vt + (size_t)bh * DD * SS;
        #pragma unroll
        for (int pass = 0; pass < 2; ++pass) {
            int c = tid + pass * 256;
            int d = c >> 3, sc = (c & 7) * 8;
            unsigned short t[8];
            #pragma unroll
            for (int u = 0; u < 8; ++u) t[u] = Ts[sc + u][d];
            uint4 o;
            o.x = (unsigned)t[0] | ((unsigned)t[1] << 16);
            o.y = (unsigned)t[2] | ((unsigned)t[3] << 16);
            o.z = (unsigned)t[4] | ((unsigned)t[5] << 16);
            o.w = (unsigned)t[6] | ((unsigned)t[7] << 16);
            *(uint4*)(Vo + (size_t)d * SS + s0 + sc) = o;
        }
    } else if (bx < 2304) {
        size_t i = ((size_t)(bx - 768) * 256 + tid) * 8;
        float4 a = *(const float4*)(K + i);
        float4 b2 = *(const float4*)(K + i + 4);
        uint4 o;
        o.x = (unsigned short)f2bf(a.x)  | ((unsigned)(unsigned short)f2bf(a.y)  << 16);
        o.y = (unsigned short)f2bf(a.z)  | ((unsigned)(unsigned short)f2bf(a.w)  << 16);
        o.z = (unsigned short)f2bf(b2.x) | ((unsigned)(unsigned short)f2bf(b2.y) << 16);
        o.w = (unsigned short)f2bf(b2.z) | ((unsigned)(unsigned short)f2bf(b2.w) << 16);
        *(uint4*)(Kb + i) = o;
    }
}

// ---------- main flash-attention kernel (partial over key group g) ----------
__global__ __launch_bounds__(256, 4) void attn_fwd(
    const float* __restrict__ Q, const unsigned short* __restrict__ Kb,
    const unsigned short* __restrict__ Vt, const u64* __restrict__ Mbt,
    float* __restrict__ Opart, float* __restrict__ Lpart)
{
    __shared__ unsigned short Ks[BK * DD];    // swizzled
    __shared__ unsigned short Vts[DD * BK];   // swizzled
    __shared__ unsigned short Ps[BQ][LP];

    const int tid  = threadIdx.x;
    const int w    = tid >> 6;        // wave 0..3, owns q rows [w*16, w*16+16)
    const int lane = tid & 63;
    const int quad = lane >> 4;
    const int l16  = lane & 15;
    const int q0   = blockIdx.x * BQ;
    const int bh   = blockIdx.y;
    const int g    = blockIdx.z;
    const int b    = bh / HH;
    const int qbase = w * 16;

    const float*          Qg  = Q   + (size_t)bh * SS * DD;
    const unsigned short* Kg  = Kb  + (size_t)bh * SS * DD;
    const unsigned short* Vg  = Vt  + (size_t)bh * DD * SS;
    const u64*            Mgt = Mbt + (size_t)b * 32 * SS;
    float* Og = Opart + ((size_t)g * BB * HH + bh) * SS * DD;
    float* Lg = Lpart + (size_t)g * NROWS + (size_t)bh * SS;

    // ---- loop-invariant Q B-frags (rows q), 1/8 scale folded (exact)
    const int qrow = q0 + qbase + l16;
    bf8_t bq[2];
    #pragma unroll
    for (int ks = 0; ks < 2; ++ks) {
        const float* qp = Qg + (size_t)qrow * DD + ks * 32 + quad * 8;
        float4 x = *(const float4*)qp;
        float4 y = *(const float4*)(qp + 4);
        bf8_t f;
        f[0] = f2bf(x.x * 0.125f); f[1] = f2bf(x.y * 0.125f);
        f[2] = f2bf(x.z * 0.125f); f[3] = f2bf(x.w * 0.125f);
        f[4] = f2bf(y.x * 0.125f); f[5] = f2bf(y.y * 0.125f);
        f[6] = f2bf(y.z * 0.125f); f[7] = f2bf(y.w * 0.125f);
        bq[ks] = f;
    }

    // ---- ones column B-frag -> row-sum l in D col 0
    bf8_t onesf;
    {
        short ov = (l16 == 0) ? (short)0x3F80 : (short)0;
        #pragma unroll
        for (int j = 0; j < 8; ++j) onesf[j] = ov;
    }

    f4_t oacc[4], lacc;
    lacc = (f4_t){0.f, 0.f, 0.f, 0.f};
    #pragma unroll
    for (int nf = 0; nf < 4; ++nf) oacc[nf] = (f4_t){0.f, 0.f, 0.f, 0.f};

    u64 mpf = Mgt[(size_t)(g * NTG) * SS + qrow];

    for (int t = 0; t < NTG; ++t) {
        const int k0 = g * KG + t * BK;
        __syncthreads();                 // prior tile's LDS readers done
        // ---- async global->LDS staging (swizzled; lane-contiguous chunks)
        #pragma unroll
        for (int j = 0; j < 2; ++j) {
            const int bc = (w * 2 + j) * 64;     // wave-uniform chunk base
            const int c  = bc + lane;
            const int r  = c >> 3;
            const int c8 = (c & 7) ^ (r & 7);
            gl_lds16(Kg + (size_t)(k0 + r) * DD + c8 * 8, &Ks[bc * 8]);
            gl_lds16(Vg + (size_t)r * SS + k0 + c8 * 8, &Vts[bc * 8]);
        }
        const u64 cm = mpf >> (quad * 4);
        __syncthreads();                 // vmcnt drained: tiles visible
        if (t + 1 < NTG)                 // mask prefetch flies during compute
            mpf = Mgt[(size_t)(g * NTG + t + 1) * SS + qrow];

        // ---- S^T = K_tile . Q^T : D[k][q], kf=0..3
        f4_t sacc[4];
        #pragma unroll
        for (int kf = 0; kf < 4; ++kf) {
            bf8_t ak0 = ldfrag(Ks, kf * 16 + l16, quad);
            bf8_t ak1 = ldfrag(Ks, kf * 16 + l16, 4 + quad);
            f4_t a = (f4_t){0.f, 0.f, 0.f, 0.f};
            a = __builtin_amdgcn_mfma_f32_16x16x32_bf16(ak0, bq[0], a, 0, 0, 0);
            a = __builtin_amdgcn_mfma_f32_16x16x32_bf16(ak1, bq[1], a, 0, 0, 0);
            sacc[kf] = a;
        }

        // ---- masked exp; lane holds k = kf*16+quad*4+r for q = qbase+l16
        const int prow = qbase + l16;
        #pragma unroll
        for (int kf = 0; kf < 4; ++kf) {
            bf4_t pk;
            #pragma unroll
            for (int r = 0; r < 4; ++r) {
                float e = __expf(sacc[kf][r]);
                e = ((cm >> (kf * 16 + r)) & 1ull) ? e : 0.f;
                pk[r] = f2bf(e);
            }
            *(bf4_t*)&Ps[prow][kf * 16 + quad * 4] = pk;
        }

        // ---- P A-frags (wave-private rows; in-order LDS: no barrier)
        bf8_t ap0 = *(const bf8_t*)&Ps[prow][quad * 8];
        bf8_t ap1 = *(const bf8_t*)&Ps[prow][32 + quad * 8];
        lacc = __builtin_amdgcn_mfma_f32_16x16x32_bf16(ap0, onesf, lacc, 0, 0, 0);
        lacc = __builtin_amdgcn_mfma_f32_16x16x32_bf16(ap1, onesf, lacc, 0, 0, 0);

        // ---- PV
        #pragma unroll
        for (int nf = 0; nf < 4; ++nf) {
            bf8_t bv0 = ldfrag(Vts, nf * 16 + l16, quad);
            bf8_t bv1 = ldfrag(Vts, nf * 16 + l16, 4 + quad);
            oacc[nf] = __builtin_amdgcn_mfma_f32_16x16x32_bf16(ap0, bv0, oacc[nf], 0, 0, 0);
            oacc[nf] = __builtin_amdgcn_mfma_f32_16x16x32_bf16(ap1, bv1, oacc[nf], 0, 0, 0);
        }
    }

    // ---- epilogue: store unnormalized O partial + l partial
    #pragma unroll
    for (int r = 0; r < 4; ++r) {
        const int row = q0 + qbase + quad * 4 + r;
        #pragma unroll
        for (int nf = 0; nf < 4; ++nf)
            Og[(size_t)row * DD + nf * 16 + l16] = oacc[nf][r];
    }
    if (l16 == 0) {
        #pragma unroll
        for (int r = 0; r < 4; ++r)
            Lg[q0 + qbase + quad * 4 + r] = lacc[r];
    }
}

// ---------- reduce: O = (O_g0 + O_g1) / (l_g0 + l_g1) ----------
__global__ __launch_bounds__(256) void reduce_o(
    const float* __restrict__ Opart, const float* __restrict__ Lpart,
    float* __restrict__ O)
{
    const size_t idx = (size_t)blockIdx.x * 256 + threadIdx.x;  // float4 units
    const size_t row = idx >> 4;
    const int    c   = (int)(idx & 15) * 4;
    const float* p0 = Opart + row * DD + c;
    const float* p1 = p0 + (size_t)NROWS * DD;
    float4 a = *(const float4*)p0;
    float4 b = *(const float4*)p1;
    const float inv = 1.f / (Lpart[row] + Lpart[NROWS + row]);
    float4 o;
    o.x = (a.x + b.x) * inv;
    o.y = (a.y + b.y) * inv;
    o.z = (a.z + b.z) * inv;
    o.w = (a.w + b.w) * inv;
    *(float4*)(O + row * DD + c) = o;
}

extern "C" void kernel_launch(void* const* d_in, const int* in_sizes, int n_in,
                              void* d_out, int out_size, void* d_ws, size_t ws_size,
                              hipStream_t stream) {
    const float* Q = (const float*)d_in[0];
    const float* K = (const float*)d_in[1];
    const float* V = (const float*)d_in[2];
    const int*   M = (const int*)d_in[3];
    float*       O = (float*)d_out;

    unsigned short* Vt = (unsigned short*)d_ws;                      // 6.29 MB
    unsigned short* Kb = Vt + (size_t)BB * HH * SS * DD;             // 6.29 MB
    u64*            Mbt = (u64*)(Kb + (size_t)BB * HH * SS * DD);    // 1.05 MB
    float*          Opart = (float*)(Mbt + (size_t)BB * 32 * SS);    // 25.2 MB
    float*          Lpart = Opart + (size_t)GG * NROWS * DD;         // 0.39 MB

    prepass<<<dim3(BB * SS), 256, 0, stream>>>(V, K, M, Vt, Kb, Mbt);
    attn_fwd<<<dim3(SS / BQ, BB * HH, GG), 256, 0, stream>>>(Q, Kb, Vt, Mbt,
                                                             Opart, Lpart);
    reduce_o<<<dim3((NROWS * DD / 4) / 256), 256, 0, stream>>>(Opart, Lpart, O);
}